// Round 8
// baseline (4289.270 us; speedup 1.0000x reference)
//
#include <hip/hip_runtime.h>
#include <math.h>

namespace {
constexpr int B_ = 128;
constexpr int T_ = 256;
constexpr int D_ = 512;
constexpr int U_ = 1024;
constexpr int N3U = 3 * U_;        // 3072
constexpr int K_TOT = D_ + U_;     // 1536
constexpr int NBG = 4;             // b-groups (M=32 each)
constexpr int NUB = 64;            // u-blocks per group (16 u each)
constexpr int WROWS = 48;          // 3 gates x 16 u
constexpr int ROWB = 3088;         // LDS row stride bytes: (1536+8)*2
constexpr int EXCH_OFF = WROWS * ROWB;          // 148224
constexpr int LDS_BYTES = EXCH_OFF + 6 * 2048;  // 160512
constexpr int POLL_LIM = 1 << 20;
}

#define E_CONST 2.71828182845904523536f

using bf16x8 = __attribute__((ext_vector_type(8))) short;
using f32x4  = __attribute__((ext_vector_type(4))) float;
using u64x2  = __attribute__((ext_vector_type(2))) unsigned long long;

__device__ inline unsigned short f2bf(float f) {
    union { float f; unsigned int u; } a; a.f = f;
    unsigned int u = a.u;
    return (unsigned short)((u + 0x7FFFu + ((u >> 16) & 1u)) >> 16);  // RNE
}

__device__ inline bf16x8 cvt8(const float* src) {
    float v[8];
    *reinterpret_cast<float4*>(&v[0]) = *reinterpret_cast<const float4*>(src);
    *reinterpret_cast<float4*>(&v[4]) = *reinterpret_cast<const float4*>(src + 4);
    bf16x8 r;
    #pragma unroll
    for (int j = 0; j < 8; ++j) r[j] = (short)f2bf(v[j]);
    return r;
}

// ---- one-time prep: WcatT[n][k] = bf16( k<512 ? Wk[k][n] : Wr[k-512][n] ) ----
__global__ void wprep(const float* __restrict__ Wk, const float* __restrict__ Wr,
                      unsigned short* __restrict__ WcatT) {
    __shared__ unsigned short S[32][33];
    const int kb = blockIdx.x * 32;
    const int nb = blockIdx.y * 32;
    const int tx = threadIdx.x;
    const int ty = threadIdx.y;
    #pragma unroll
    for (int j = 0; j < 4; ++j) {
        const int r = ty + 8 * j;
        const int k = kb + r;
        const int n = nb + tx;
        const float v = (k < D_) ? Wk[(size_t)k * N3U + n]
                                 : Wr[(size_t)(k - D_) * N3U + n];
        S[tx][r] = f2bf(v);
    }
    __syncthreads();
    #pragma unroll
    for (int j = 0; j < 4; ++j) {
        const int r = ty + 8 * j;
        WcatT[(size_t)(nb + r) * K_TOT + kb + tx] = S[r][tx];
    }
}

// ---- persistent kernel: per-producer flags; h via agent-coherent loads ----
// 256 blocks; XCD-clustered: bg = (bid>>1)&3, ub = (bid>>3)*2 + (bid&1)
// (consecutive bids round-robin XCDs -> group g occupies XCDs {2g, 2g+1}).
// Waves 0-5: (bt = w&1, gate g = w>>1) GEMM over K=1536 from LDS weights.
// Wave 6: epilogue half. Wave 7: poller + epilogue half.
__global__ __launch_bounds__(512) void tgru_flags3(
    const float* __restrict__ seq,            // [B,T,D] fp32
    const float* __restrict__ dts,            // [B,T]
    const unsigned short* __restrict__ WcatT, // [3072][1536] bf16
    const float* __restrict__ ib,             // [3U]
    const float* __restrict__ rb,             // [3U]
    unsigned short* hbA,                      // h*dec bf16 (h at even t)
    unsigned short* hbB,                      // h at odd t
    unsigned int* flags,                      // [NBG*64] x 16 u32 (64B lines)
    float* __restrict__ out)                  // [B,U]
{
    extern __shared__ char lds[];

    const int tid  = threadIdx.x;
    const int lane = tid & 63;
    const int w    = tid >> 6;
    const int l15  = lane & 15;
    const int lk   = lane >> 4;
    const int bid  = blockIdx.x;
    const int bg   = (bid >> 1) & 3;               // XCD-clustered group
    const int ub   = ((bid >> 3) << 1) | (bid & 1);
    const int u0   = ub * 16;

    // ---- stage weights: 48 rows x 1536 k into LDS (padded rows) ----
    for (int idx = tid; idx < WROWS * 192; idx += 512) {
        const int c = idx / 192;          // row 0..47
        const int o = idx % 192;          // 16B chunk
        const unsigned short* src =
            WcatT + (size_t)((c >> 4) * U_ + u0 + (c & 15)) * K_TOT + o * 8;
        *reinterpret_cast<bf16x8*>(lds + (size_t)c * ROWB + o * 16) =
            *reinterpret_cast<const bf16x8*>(src);
    }
    __syncthreads();

    float* exf = reinterpret_cast<float*>(lds + EXCH_OFF);

    // ---- epilogue-wave constants ----
    const int up = lane & 7;          // u-pair index
    const int rg = lane >> 3;         // 0..7 row-group
    float bzs[2], brs[2], ibh_[2], rbh_[2];
    float hreg[2][2] = {{0.f, 0.f}, {0.f, 0.f}};
    if (w >= 6) {
        #pragma unroll
        for (int f = 0; f < 2; ++f) {
            const int u = u0 + 2 * up + f;
            bzs[f]  = ib[u] + rb[u];
            brs[f]  = ib[U_ + u] + rb[U_ + u];
            ibh_[f] = ib[2 * U_ + u];
            rbh_[f] = rb[2 * U_ + u];
        }
    }
    unsigned int* myflag = flags + ((bg << 6) + ub) * 16 + (w - 6);

    for (int t = 0; t < T_; ++t) {
        const unsigned short* hbp = (t & 1) ? hbB : hbA;   // h(t)
        unsigned short*       hbn = (t & 1) ? hbA : hbB;   // h(t+1)
        float decn[2];

        f32x4 aX = {0.f, 0.f, 0.f, 0.f};
        f32x4 aH = {0.f, 0.f, 0.f, 0.f};
        const char* wrow = lds + (size_t)((w >> 1) * 16 + l15) * ROWB + 16 * lk;
        const int bgemm = bg * 32 + (w & 1) * 16 + l15;

        if (w < 6) {
            // x-part (k in [0,512)) — overlaps wave 7's poll
            const float* ap = seq + ((size_t)bgemm * T_ + t) * D_ + 8 * lk;
            #pragma unroll 8
            for (int ks = 0; ks < 16; ++ks) {
                const bf16x8 a = cvt8(ap + 32 * ks);
                const bf16x8 bf = *reinterpret_cast<const bf16x8*>(wrow + 64 * ks);
                aX = __builtin_amdgcn_mfma_f32_16x16x32_bf16(a, bf, aX, 0, 0, 0);
            }
        } else {
            // decay prefetch for t+1
            const int tn = (t < T_ - 1) ? t + 1 : t;
            #pragma unroll
            for (int e = 0; e < 2; ++e) {
                const int b = bg * 32 + (w - 6) * 16 + rg * 2 + e;
                decn[e] = 1.0f / logf(E_CONST + dts[b * T_ + tn]);
            }
            if (w == 7 && t > 0) {
                // poll all 64 producers x 2 halves of this b-group
                const unsigned long long* fl =
                    (const unsigned long long*)(flags + ((bg << 6) + lane) * 16);
                int guard = 0;
                for (;;) {
                    const unsigned long long v = __hip_atomic_load(
                        fl, __ATOMIC_RELAXED, __HIP_MEMORY_SCOPE_AGENT);
                    const int ok = ((unsigned)(v & 0xffffffffu) >= (unsigned)t) &&
                                   ((unsigned)(v >> 32)         >= (unsigned)t);
                    if (__all(ok)) break;
                    if (++guard > POLL_LIM) break;   // safety: no hang
                }
                // NO agent acquire fence: h is read with coherent loads below.
                __builtin_amdgcn_fence(__ATOMIC_ACQUIRE, "workgroup");
            }
        }

        __syncthreads();   // B1: flag confirmed; L2 stays warm

        if (w < 6) {
            if (t > 0) {
                // h-part (k in [512,1536)): agent-coherent 8B loads (bypass L1/L2)
                const unsigned long long* hp64 =
                    reinterpret_cast<const unsigned long long*>(
                        hbp + (size_t)bgemm * U_ + 8 * lk);
                #pragma unroll 8
                for (int ks = 0; ks < 32; ++ks) {
                    u64x2 q;
                    q.x = __hip_atomic_load(hp64 + 8 * ks, __ATOMIC_RELAXED,
                                            __HIP_MEMORY_SCOPE_AGENT);
                    q.y = __hip_atomic_load(hp64 + 8 * ks + 1, __ATOMIC_RELAXED,
                                            __HIP_MEMORY_SCOPE_AGENT);
                    const bf16x8 a = __builtin_bit_cast(bf16x8, q);
                    const bf16x8 bf = *reinterpret_cast<const bf16x8*>(
                        wrow + 1024 + 64 * ks);
                    aH = __builtin_amdgcn_mfma_f32_16x16x32_bf16(a, bf, aH, 0, 0, 0);
                }
            }
            *reinterpret_cast<f32x4*>(&exf[w * 512 + lane * 4]) = aX;
            *reinterpret_cast<f32x4*>(&exf[w * 512 + 256 + lane * 4]) = aH;
        }

        __syncthreads();   // B2: exchange ready

        if (w >= 6) {
            const int bt = w - 6;
            #pragma unroll
            for (int e = 0; e < 2; ++e) {
                const int bl  = rg * 2 + e;
                const int b   = bg * 32 + bt * 16 + bl;
                const int lkq = (bl >> 2) * 16;
                const int q   = bl & 3;
                float hn2[2];
                #pragma unroll
                for (int f = 0; f < 2; ++f) {
                    const int ul = 2 * up + f;
                    const int i0 = (0 * 2 + bt) * 512 + (lkq + ul) * 4 + q;
                    const int i1 = (1 * 2 + bt) * 512 + (lkq + ul) * 4 + q;
                    const int i2 = (2 * 2 + bt) * 512 + (lkq + ul) * 4 + q;
                    const float z  = 1.0f / (1.0f + expf(-(exf[i0] + exf[i0 + 256] + bzs[f])));
                    const float r  = 1.0f / (1.0f + expf(-(exf[i1] + exf[i1 + 256] + brs[f])));
                    const float hh = tanhf(exf[i2] + ibh_[f] + r * (exf[i2 + 256] + rbh_[f]));
                    hn2[f] = z * hreg[e][f] + (1.0f - z) * hh;
                }
                if (t == T_ - 1) {
                    *reinterpret_cast<float2*>(&out[(size_t)b * U_ + u0 + 2 * up]) =
                        make_float2(hn2[0], hn2[1]);
                } else {
                    const float hd0 = hn2[0] * decn[e];
                    const float hd1 = hn2[1] * decn[e];
                    hreg[e][0] = hd0;     // fp32 state stays in regs
                    hreg[e][1] = hd1;
                    const unsigned int pk =
                        (unsigned int)f2bf(hd0) | ((unsigned int)f2bf(hd1) << 16);
                    __hip_atomic_store(
                        reinterpret_cast<unsigned int*>(&hbn[(size_t)b * U_ + u0 + 2 * up]),
                        pk, __ATOMIC_RELAXED, __HIP_MEMORY_SCOPE_AGENT);
                }
            }
            if (t < T_ - 1) {
                asm volatile("s_waitcnt vmcnt(0)" ::: "memory");  // h stores at L3
                if (lane == 0) {
                    __hip_atomic_store(myflag, (unsigned int)(t + 1),
                                       __ATOMIC_RELAXED, __HIP_MEMORY_SCOPE_AGENT);
                }
            }
        }
    }
}

extern "C" void kernel_launch(void* const* d_in, const int* in_sizes, int n_in,
                              void* d_out, int out_size, void* d_ws, size_t ws_size,
                              hipStream_t stream) {
    const float* seq = (const float*)d_in[0];
    const float* dts = (const float*)d_in[1];
    const float* Wk  = (const float*)d_in[2];
    const float* Wr  = (const float*)d_in[3];
    const float* ib  = (const float*)d_in[4];
    const float* rb  = (const float*)d_in[5];
    float* out = (float*)d_out;

    char* wsb = (char*)d_ws;
    // ws layout (bytes):
    //   [0,       9437184)   WcatT bf16 [3072][1536]
    //   [9437184, 9699328)   hbA bf16 [128][1024]  (not read at t=0)
    //   [9699328, 9961472)   hbB
    //   [9961472, 9977856)   flags: 256 blocks x 64 B
    unsigned short* wcat = (unsigned short*)(wsb);
    unsigned short* hbA  = (unsigned short*)(wsb + 9437184);
    unsigned short* hbB  = (unsigned short*)(wsb + 9699328);
    unsigned int*   flags = (unsigned int*)(wsb + 9961472);

    // flags must be 0 at start of every replay (monotonic within a launch)
    hipMemsetAsync(flags, 0, 16384, stream);

    wprep<<<dim3(K_TOT / 32, N3U / 32), dim3(32, 8), 0, stream>>>(Wk, Wr, wcat);

    hipFuncSetAttribute((const void*)tgru_flags3,
                        hipFuncAttributeMaxDynamicSharedMemorySize, LDS_BYTES);

    void* args[] = {
        (void*)&seq, (void*)&dts, (void*)&wcat, (void*)&ib, (void*)&rb,
        (void*)&hbA, (void*)&hbB, (void*)&flags, (void*)&out
    };
    hipLaunchCooperativeKernel((void*)tgru_flags3, dim3(NBG * NUB), dim3(512),
                               args, LDS_BYTES, stream);
}

// Round 9
// 3165.623 us; speedup vs baseline: 1.3550x; 1.3550x over previous
//
#include <hip/hip_runtime.h>
#include <math.h>

namespace {
constexpr int B_ = 128;
constexpr int T_ = 256;
constexpr int D_ = 512;
constexpr int U_ = 1024;
constexpr int N3U = 3 * U_;        // 3072
constexpr int K_TOT = D_ + U_;     // 1536
constexpr int NBG = 4;             // b-groups (M=32 each)
constexpr int NUB = 64;            // u-blocks per group (16 u each)
constexpr int WROWS = 48;          // 3 gates x 16 u
constexpr int ROWB = 3088;         // LDS row stride bytes: (1536+8)*2
constexpr int EXCH_OFF = WROWS * ROWB;          // 148224
constexpr int LDS_BYTES = EXCH_OFF + 6 * 2048;  // 160512
constexpr int POLL_LIM = 1 << 20;
}

#define E_CONST 2.71828182845904523536f

using bf16x8 = __attribute__((ext_vector_type(8))) short;
using f32x4  = __attribute__((ext_vector_type(4))) float;

__device__ inline unsigned short f2bf(float f) {
    union { float f; unsigned int u; } a; a.f = f;
    unsigned int u = a.u;
    return (unsigned short)((u + 0x7FFFu + ((u >> 16) & 1u)) >> 16);  // RNE
}

__device__ inline bf16x8 cvt8(const float* src) {
    float v[8];
    *reinterpret_cast<float4*>(&v[0]) = *reinterpret_cast<const float4*>(src);
    *reinterpret_cast<float4*>(&v[4]) = *reinterpret_cast<const float4*>(src + 4);
    bf16x8 r;
    #pragma unroll
    for (int j = 0; j < 8; ++j) r[j] = (short)f2bf(v[j]);
    return r;
}

// Issue 8 coherent (L1/L2-bypass) 16B loads at base + G*512 + j*64 bytes.
#define ISSUE8(arr, base, G)                                                   \
    {                                                                          \
        _Pragma("unroll")                                                      \
        for (int j = 0; j < 8; ++j) {                                          \
            asm volatile("global_load_dwordx4 %0, %1, off offset:%2 sc0 sc1"   \
                         : "=&v"(arr[j])                                       \
                         : "v"(base), "i"((G) * 512 + j * 64));                \
        }                                                                      \
    }

// Pin: re-def each value AFTER the preceding waitcnt (volatile-asm ordered),
// so MFMAs can't be hoisted above the wait (rule: "memory" doesn't order VGPRs).
#define PIN8(arr)                                                              \
    {                                                                          \
        _Pragma("unroll")                                                      \
        for (int j = 0; j < 8; ++j) asm volatile("" : "+v"(arr[j]));           \
    }

#define WAITV(N) asm volatile("s_waitcnt vmcnt(" #N ")" ::: "memory")

// ---- one-time prep: WcatT[n][k] = bf16( k<512 ? Wk[k][n] : Wr[k-512][n] ) ----
__global__ void wprep(const float* __restrict__ Wk, const float* __restrict__ Wr,
                      unsigned short* __restrict__ WcatT) {
    __shared__ unsigned short S[32][33];
    const int kb = blockIdx.x * 32;
    const int nb = blockIdx.y * 32;
    const int tx = threadIdx.x;
    const int ty = threadIdx.y;
    #pragma unroll
    for (int j = 0; j < 4; ++j) {
        const int r = ty + 8 * j;
        const int k = kb + r;
        const int n = nb + tx;
        const float v = (k < D_) ? Wk[(size_t)k * N3U + n]
                                 : Wr[(size_t)(k - D_) * N3U + n];
        S[tx][r] = f2bf(v);
    }
    __syncthreads();
    #pragma unroll
    for (int j = 0; j < 4; ++j) {
        const int r = ty + 8 * j;
        WcatT[(size_t)(nb + r) * K_TOT + kb + tx] = S[r][tx];
    }
}

// ---- persistent kernel: per-producer flags; h via batched coherent loads ----
// 256 blocks; XCD-clustered: bg = (bid>>1)&3, ub = (bid>>3)*2 + (bid&1).
// Waves 0-5: (bt = w&1, gate g = w>>1) GEMM over K=1536 from LDS weights.
// Wave 6: epilogue half. Wave 7: poller + epilogue half.
__global__ __launch_bounds__(512) void tgru_flags4(
    const float* __restrict__ seq,            // [B,T,D] fp32
    const float* __restrict__ dts,            // [B,T]
    const unsigned short* __restrict__ WcatT, // [3072][1536] bf16
    const float* __restrict__ ib,             // [3U]
    const float* __restrict__ rb,             // [3U]
    unsigned short* hbA,                      // h*dec bf16 (h at even t)
    unsigned short* hbB,                      // h at odd t
    unsigned int* flags,                      // [NBG*64] x 16 u32 (64B lines)
    float* __restrict__ out)                  // [B,U]
{
    extern __shared__ char lds[];

    const int tid  = threadIdx.x;
    const int lane = tid & 63;
    const int w    = tid >> 6;
    const int l15  = lane & 15;
    const int lk   = lane >> 4;
    const int bid  = blockIdx.x;
    const int bg   = (bid >> 1) & 3;               // XCD-clustered group
    const int ub   = ((bid >> 3) << 1) | (bid & 1);
    const int u0   = ub * 16;

    // ---- stage weights: 48 rows x 1536 k into LDS (padded rows) ----
    for (int idx = tid; idx < WROWS * 192; idx += 512) {
        const int c = idx / 192;          // row 0..47
        const int o = idx % 192;          // 16B chunk
        const unsigned short* src =
            WcatT + (size_t)((c >> 4) * U_ + u0 + (c & 15)) * K_TOT + o * 8;
        *reinterpret_cast<bf16x8*>(lds + (size_t)c * ROWB + o * 16) =
            *reinterpret_cast<const bf16x8*>(src);
    }
    __syncthreads();

    float* exf = reinterpret_cast<float*>(lds + EXCH_OFF);

    // ---- epilogue-wave constants ----
    const int up = lane & 7;          // u-pair index
    const int rg = lane >> 3;         // 0..7 row-group
    float bzs[2], brs[2], ibh_[2], rbh_[2];
    float hreg[2][2] = {{0.f, 0.f}, {0.f, 0.f}};
    if (w >= 6) {
        #pragma unroll
        for (int f = 0; f < 2; ++f) {
            const int u = u0 + 2 * up + f;
            bzs[f]  = ib[u] + rb[u];
            brs[f]  = ib[U_ + u] + rb[U_ + u];
            ibh_[f] = ib[2 * U_ + u];
            rbh_[f] = rb[2 * U_ + u];
        }
    }
    unsigned int* myflag = flags + ((bg << 6) + ub) * 16 + (w - 6);

    #pragma unroll 1
    for (int t = 0; t < T_; ++t) {
        const unsigned short* hbp = (t & 1) ? hbB : hbA;   // h(t)
        unsigned short*       hbn = (t & 1) ? hbA : hbB;   // h(t+1)
        float decn[2];

        f32x4 aX = {0.f, 0.f, 0.f, 0.f};
        f32x4 aH = {0.f, 0.f, 0.f, 0.f};
        const char* wrow = lds + (size_t)((w >> 1) * 16 + l15) * ROWB + 16 * lk;
        const int bgemm = bg * 32 + (w & 1) * 16 + l15;

        if (w < 6) {
            // x-part (k in [0,512)) — overlaps wave 7's poll
            const float* ap = seq + ((size_t)bgemm * T_ + t) * D_ + 8 * lk;
            #pragma unroll 8
            for (int ks = 0; ks < 16; ++ks) {
                const bf16x8 a = cvt8(ap + 32 * ks);
                const bf16x8 bf = *reinterpret_cast<const bf16x8*>(wrow + 64 * ks);
                aX = __builtin_amdgcn_mfma_f32_16x16x32_bf16(a, bf, aX, 0, 0, 0);
            }
        } else {
            // decay prefetch for t+1
            const int tn = (t < T_ - 1) ? t + 1 : t;
            #pragma unroll
            for (int e = 0; e < 2; ++e) {
                const int b = bg * 32 + (w - 6) * 16 + rg * 2 + e;
                decn[e] = 1.0f / logf(E_CONST + dts[b * T_ + tn]);
            }
            if (w == 7 && t > 0) {
                // poll all 64 producers x 2 halves of this b-group
                const unsigned long long* fl =
                    (const unsigned long long*)(flags + ((bg << 6) + lane) * 16);
                int guard = 0;
                for (;;) {
                    const unsigned long long v = __hip_atomic_load(
                        fl, __ATOMIC_RELAXED, __HIP_MEMORY_SCOPE_AGENT);
                    const int ok = ((unsigned)(v & 0xffffffffu) >= (unsigned)t) &&
                                   ((unsigned)(v >> 32)         >= (unsigned)t);
                    if (__all(ok)) break;
                    if (++guard > POLL_LIM) break;   // safety: no hang
                }
                __builtin_amdgcn_fence(__ATOMIC_ACQUIRE, "workgroup");
            }
        }

        __syncthreads();   // B1: h(t) published; L2 stays warm (no inv)

        if (w < 6) {
            if (t > 0) {
                // h-part (k in [512,1536)): 32 coherent 16B loads, all in
                // flight, consumed in 4 groups gated by counted vmcnt.
                const char* hbase =
                    (const char*)(hbp + (size_t)bgemm * U_ + 8 * lk);
                bf16x8 h0[8], h1[8], h2[8], h3[8];
                ISSUE8(h0, hbase, 0)
                ISSUE8(h1, hbase, 1)
                ISSUE8(h2, hbase, 2)
                ISSUE8(h3, hbase, 3)

                WAITV(24); PIN8(h0)
                #pragma unroll
                for (int j = 0; j < 8; ++j) {
                    const bf16x8 bf = *reinterpret_cast<const bf16x8*>(
                        wrow + 1024 + 64 * (0 * 8 + j));
                    aH = __builtin_amdgcn_mfma_f32_16x16x32_bf16(h0[j], bf, aH, 0, 0, 0);
                }
                WAITV(16); PIN8(h1)
                #pragma unroll
                for (int j = 0; j < 8; ++j) {
                    const bf16x8 bf = *reinterpret_cast<const bf16x8*>(
                        wrow + 1024 + 64 * (1 * 8 + j));
                    aH = __builtin_amdgcn_mfma_f32_16x16x32_bf16(h1[j], bf, aH, 0, 0, 0);
                }
                WAITV(8); PIN8(h2)
                #pragma unroll
                for (int j = 0; j < 8; ++j) {
                    const bf16x8 bf = *reinterpret_cast<const bf16x8*>(
                        wrow + 1024 + 64 * (2 * 8 + j));
                    aH = __builtin_amdgcn_mfma_f32_16x16x32_bf16(h2[j], bf, aH, 0, 0, 0);
                }
                WAITV(0); PIN8(h3)
                #pragma unroll
                for (int j = 0; j < 8; ++j) {
                    const bf16x8 bf = *reinterpret_cast<const bf16x8*>(
                        wrow + 1024 + 64 * (3 * 8 + j));
                    aH = __builtin_amdgcn_mfma_f32_16x16x32_bf16(h3[j], bf, aH, 0, 0, 0);
                }
            }
            *reinterpret_cast<f32x4*>(&exf[w * 512 + lane * 4]) = aX;
            *reinterpret_cast<f32x4*>(&exf[w * 512 + 256 + lane * 4]) = aH;
        }

        __syncthreads();   // B2: exchange ready

        if (w >= 6) {
            const int bt = w - 6;
            #pragma unroll
            for (int e = 0; e < 2; ++e) {
                const int bl  = rg * 2 + e;
                const int b   = bg * 32 + bt * 16 + bl;
                const int lkq = (bl >> 2) * 16;
                const int q   = bl & 3;
                float hn2[2];
                #pragma unroll
                for (int f = 0; f < 2; ++f) {
                    const int ul = 2 * up + f;
                    const int i0 = (0 * 2 + bt) * 512 + (lkq + ul) * 4 + q;
                    const int i1 = (1 * 2 + bt) * 512 + (lkq + ul) * 4 + q;
                    const int i2 = (2 * 2 + bt) * 512 + (lkq + ul) * 4 + q;
                    const float z  = 1.0f / (1.0f + expf(-(exf[i0] + exf[i0 + 256] + bzs[f])));
                    const float r  = 1.0f / (1.0f + expf(-(exf[i1] + exf[i1 + 256] + brs[f])));
                    const float hh = tanhf(exf[i2] + ibh_[f] + r * (exf[i2 + 256] + rbh_[f]));
                    hn2[f] = z * hreg[e][f] + (1.0f - z) * hh;
                }
                if (t == T_ - 1) {
                    *reinterpret_cast<float2*>(&out[(size_t)b * U_ + u0 + 2 * up]) =
                        make_float2(hn2[0], hn2[1]);
                } else {
                    const float hd0 = hn2[0] * decn[e];
                    const float hd1 = hn2[1] * decn[e];
                    hreg[e][0] = hd0;     // fp32 state stays in regs
                    hreg[e][1] = hd1;
                    const unsigned int pk =
                        (unsigned int)f2bf(hd0) | ((unsigned int)f2bf(hd1) << 16);
                    __hip_atomic_store(
                        reinterpret_cast<unsigned int*>(&hbn[(size_t)b * U_ + u0 + 2 * up]),
                        pk, __ATOMIC_RELAXED, __HIP_MEMORY_SCOPE_AGENT);
                }
            }
            if (t < T_ - 1) {
                asm volatile("s_waitcnt vmcnt(0)" ::: "memory");  // h stores at L3
                if (lane == 0) {
                    __hip_atomic_store(myflag, (unsigned int)(t + 1),
                                       __ATOMIC_RELAXED, __HIP_MEMORY_SCOPE_AGENT);
                }
            }
        }
    }
}

extern "C" void kernel_launch(void* const* d_in, const int* in_sizes, int n_in,
                              void* d_out, int out_size, void* d_ws, size_t ws_size,
                              hipStream_t stream) {
    const float* seq = (const float*)d_in[0];
    const float* dts = (const float*)d_in[1];
    const float* Wk  = (const float*)d_in[2];
    const float* Wr  = (const float*)d_in[3];
    const float* ib  = (const float*)d_in[4];
    const float* rb  = (const float*)d_in[5];
    float* out = (float*)d_out;

    char* wsb = (char*)d_ws;
    // ws layout (bytes):
    //   [0,       9437184)   WcatT bf16 [3072][1536]
    //   [9437184, 9699328)   hbA bf16 [128][1024]  (not read at t=0)
    //   [9699328, 9961472)   hbB
    //   [9961472, 9977856)   flags: 256 blocks x 64 B
    unsigned short* wcat = (unsigned short*)(wsb);
    unsigned short* hbA  = (unsigned short*)(wsb + 9437184);
    unsigned short* hbB  = (unsigned short*)(wsb + 9699328);
    unsigned int*   flags = (unsigned int*)(wsb + 9961472);

    // flags must be 0 at start of every replay (monotonic within a launch)
    hipMemsetAsync(flags, 0, 16384, stream);

    wprep<<<dim3(K_TOT / 32, N3U / 32), dim3(32, 8), 0, stream>>>(Wk, Wr, wcat);

    hipFuncSetAttribute((const void*)tgru_flags4,
                        hipFuncAttributeMaxDynamicSharedMemorySize, LDS_BYTES);

    void* args[] = {
        (void*)&seq, (void*)&dts, (void*)&wcat, (void*)&ib, (void*)&rb,
        (void*)&hbA, (void*)&hbB, (void*)&flags, (void*)&out
    };
    hipLaunchCooperativeKernel((void*)tgru_flags4, dim3(NBG * NUB), dim3(512),
                               args, LDS_BYTES, stream);
}